// Round 5
// baseline (244.888 us; speedup 1.0000x reference)
//
#include <hip/hip_runtime.h>

// Fused MHA: x(4,1024,1024) fp32, mask(4,1024) i32, w_qkv(3072,1024), b_qkv,
// w_out(1024,1024), b_out -> out(4,1024,1024) fp32.
// Pipeline: prep-cast -> mask-sum -> qkv GEMM (bf16 MFMA) -> flash attn -> out GEMM.
// R5: attn = 2-wave KV-split (occupancy 2x) + LDS flash-merge; masked-tile skip;
//     diag-only mask path; exp2-domain softmax; defer-max (THR=8) rescale skip.

#define NHEADS 16
#define DHEAD  64
#define EDIM   1024
#define SLEN   1024
#define BATCH  4

typedef short bf16x8 __attribute__((ext_vector_type(8)));
typedef float f32x4  __attribute__((ext_vector_type(4)));
typedef float f32x16 __attribute__((ext_vector_type(16)));

#define MFMA_BF16(a,b,c) __builtin_amdgcn_mfma_f32_16x16x32_bf16((a),(b),(c),0,0,0)
#define MFMA32(a,b,c)    __builtin_amdgcn_mfma_f32_32x32x16_bf16((a),(b),(c),0,0,0)

typedef const __attribute__((address_space(1))) void gvoid_t;
typedef __attribute__((address_space(3))) void lvoid_t;

__device__ __forceinline__ unsigned short f2bf(float x) {
  union { float f; unsigned int u; } v; v.f = x;
  unsigned int r = v.u + 0x7fffu + ((v.u >> 16) & 1u);
  return (unsigned short)(r >> 16);
}

__device__ __forceinline__ unsigned pack2(float lo, float hi) {
  return (unsigned)f2bf(lo) | ((unsigned)f2bf(hi) << 16);
}

__device__ __forceinline__ void gl2lds16(const void* g, void* l) {
  __builtin_amdgcn_global_load_lds((gvoid_t*)g, (lvoid_t*)l, 16, 0, 0);
}

// ---------------- prep: fp32 -> bf16 casts ----------------
__global__ __launch_bounds__(256) void prep_cast(
    const float* __restrict__ x, const float* __restrict__ wq,
    const float* __restrict__ wo,
    unsigned short* __restrict__ xb, unsigned short* __restrict__ wqb,
    unsigned short* __restrict__ wob) {
  int i = blockIdx.x * 256 + threadIdx.x;
  const int NX  = BATCH * SLEN * EDIM / 4;   // 1048576
  const int NW1 = 3 * EDIM * EDIM / 4;       // 786432
  const float4* src; unsigned short* dst; int j;
  if (i < NX)           { src = (const float4*)x;  dst = xb;  j = i; }
  else if (i < NX+NW1)  { src = (const float4*)wq; dst = wqb; j = i - NX; }
  else                  { src = (const float4*)wo; dst = wob; j = i - NX - NW1; }
  float4 v = src[j];
  ushort4 o;
  o.x = f2bf(v.x); o.y = f2bf(v.y); o.z = f2bf(v.z); o.w = f2bf(v.w);
  ((ushort4*)dst)[j] = o;
}

// ---------------- mask row-sum: L[b] ----------------
__global__ __launch_bounds__(256) void mask_sum(const int* __restrict__ mask,
                                                int* __restrict__ L) {
  int b = blockIdx.x;
  int t = threadIdx.x;
  int s = 0;
  for (int i = t; i < SLEN; i += 256) s += mask[b * SLEN + i];
  #pragma unroll
  for (int m = 1; m < 64; m <<= 1) s += __shfl_xor(s, m);
  __shared__ int part[4];
  if ((t & 63) == 0) part[t >> 6] = s;
  __syncthreads();
  if (t == 0) L[b] = part[0] + part[1] + part[2] + part[3];
}

// ---------------- GEMM C = A @ B^T (A:[M][K], B:[N][K], bf16, m97 structure) ----
template<int EPI>
__global__ __launch_bounds__(256) void gemm_bt(
    const unsigned short* __restrict__ A, const unsigned short* __restrict__ B,
    int M, int N, int K,
    const float* __restrict__ bias,
    float* __restrict__ outf,
    unsigned short* __restrict__ qb, unsigned short* __restrict__ kb,
    unsigned short* __restrict__ vb) {
  __shared__ __align__(16) unsigned short lds_a[128 * 32];
  __shared__ __align__(16) unsigned short lds_b[128 * 32];
  const int tid = threadIdx.x;
  const int w = tid >> 6, l = tid & 63;
  const int g = l >> 4, ln = l & 15;
  const int ntile = N >> 7;
  const int tm = blockIdx.x / ntile, tn = blockIdx.x % ntile;
  const int mBase = tm << 7, nBase = tn << 7;
  const int wr = w >> 1, wc = w & 1;

  f32x4 zz = {0.f, 0.f, 0.f, 0.f};
  f32x4 acc[4][4];
  #pragma unroll
  for (int m = 0; m < 4; ++m)
    #pragma unroll
    for (int n = 0; n < 4; ++n) acc[m][n] = zz;

  const int u0 = tid, u1 = tid + 256;
  const int r0 = u0 >> 2, c0 = (u0 & 3) << 3;
  const int r1 = u1 >> 2, c1 = (u1 & 3) << 3;
  const unsigned short* Ab = A + mBase * K;
  const unsigned short* Bb = B + nBase * K;
  unsigned short* da0 = &lds_a[(w * 64) * 8];
  unsigned short* da1 = &lds_a[(256 + w * 64) * 8];
  unsigned short* db0 = &lds_b[(w * 64) * 8];
  unsigned short* db1 = &lds_b[(256 + w * 64) * 8];

  for (int k0 = 0; k0 < K; k0 += 32) {
    gl2lds16(Ab + r0 * K + k0 + c0, da0);
    gl2lds16(Ab + r1 * K + k0 + c1, da1);
    gl2lds16(Bb + r0 * K + k0 + c0, db0);
    gl2lds16(Bb + r1 * K + k0 + c1, db1);
    __syncthreads();
    bf16x8 af[4], bfr[4];
    #pragma unroll
    for (int m = 0; m < 4; ++m)
      af[m] = *(const bf16x8*)&lds_a[(wr * 64 + m * 16 + ln) * 32 + g * 8];
    #pragma unroll
    for (int n = 0; n < 4; ++n)
      bfr[n] = *(const bf16x8*)&lds_b[(wc * 64 + n * 16 + ln) * 32 + g * 8];
    #pragma unroll
    for (int m = 0; m < 4; ++m)
      #pragma unroll
      for (int n = 0; n < 4; ++n)
        acc[m][n] = MFMA_BF16(af[m], bfr[n], acc[m][n]);
    __syncthreads();
  }

  #pragma unroll
  for (int m = 0; m < 4; ++m) {
    const int rowb = mBase + wr * 64 + m * 16 + g * 4;
    #pragma unroll
    for (int n = 0; n < 4; ++n) {
      const int col = nBase + wc * 64 + n * 16 + ln;
      const float bv = bias[col];
      #pragma unroll
      for (int r = 0; r < 4; ++r) {
        const float vv = acc[m][n][r] + bv;
        const int row = rowb + r;
        if (EPI == 0) {
          const int part = col >> 10;          // 0=q,1=k,2=v
          const int c = col & 1023;
          const int hh = c >> 6, d = c & 63;
          const int bb = row >> 10, s = row & 1023;
          const int bh = bb * NHEADS + hh;
          const unsigned short hv = f2bf(vv);
          if (part == 0)      qb[(bh * SLEN + s) * DHEAD + d] = hv;
          else if (part == 1) kb[(bh * SLEN + s) * DHEAD + d] = hv;
          else                vb[(bh * DHEAD + d) * SLEN + s] = hv;  // V^T
        } else {
          outf[row * N + col] = vv;
        }
      }
    }
  }
}

// ---------------- flash attention (swapped-operand 32x32, KV-split x2) --------
// 128-thr blocks = 2 waves; wave w does key-tiles t==w (mod 2); LDS flash-merge.
// S^T = mfma(K, Q): lane holds q=lane&31, keys crow(r,hi)=(r&3)+8*(r>>2)+4*hi.
// O^T = mfma(V^T, P): lane holds q=lane&31, d=crow(r,hi) (+32 for o1).
__global__ __launch_bounds__(128) void attn(
    const unsigned short* __restrict__ qb, const unsigned short* __restrict__ kb,
    const unsigned short* __restrict__ vb, const int* __restrict__ Lp,
    unsigned short* __restrict__ yb) {
  const int bid = blockIdx.x;
  const int lid = (bid & 7) * 256 + (bid >> 3);   // XCD-chunked swizzle (2048%8==0)
  const int bh = lid >> 5, qw = lid & 31;
  const int b = bh >> 4, h = bh & 15;
  const int L = Lp[b];
  const int tid = threadIdx.x;
  const int w = tid >> 6, l = tid & 63;
  const int l31 = l & 31, hi = l >> 5;
  const int q = qw * 32 + l31;

  const unsigned short* qp = qb + (size_t)bh * SLEN * DHEAD;
  const unsigned short* kp = kb + (size_t)bh * SLEN * DHEAD;
  const unsigned short* vp = vb + (size_t)bh * DHEAD * SLEN;

  // Q B-frags: B[k=dh][col=q], lane: Q[q][c*16 + hi*8 + j]
  bf16x8 qf[4];
  #pragma unroll
  for (int c = 0; c < 4; ++c)
    qf[c] = *(const bf16x8*)&qp[q * DHEAD + c * 16 + hi * 8];

  f32x16 o0 = {}; f32x16 o1 = {};
  float mrow = -__builtin_inff(), lrow = 0.f;   // mrow in log2 domain
  const bool qv = q < L;
  const float C = 0.18033688011112042f;         // 0.125 * log2(e)

  // wave-uniform mask classification
  const bool allQ   = (qw * 32 + 31) < L;       // all rows masked-eligible
  const bool noneQ  = (qw * 32) >= L;           // no row masked
  const bool skipOK = allQ && (L < SLEN);       // fully-masked tiles skippable

  for (int t = w; t < 32; t += 2) {
    if (skipOK && t < qw) continue;             // fully masked tile: exact no-op
    const int kb0 = t * 32;
    // --- QK^T (swapped): A = K rows (key=lane&31), B = Q ---
    f32x16 e = {};
    __builtin_amdgcn_s_setprio(1);
    #pragma unroll
    for (int c = 0; c < 4; ++c) {
      const bf16x8 kf = *(const bf16x8*)&kp[(kb0 + l31) * DHEAD + c * 16 + hi * 8];
      e = MFMA32(kf, qf[c], e);
    }
    __builtin_amdgcn_s_setprio(0);

    // --- scale (exp2 domain) + mask (diagonal tiles only) + row max ---
    const bool domask = (!noneQ) && (t <= qw);
    float pm = -__builtin_inff();
    if (domask) {
      #pragma unroll
      for (int r = 0; r < 16; ++r) {
        const int key = kb0 + (r & 3) + 8 * (r >> 2) + 4 * hi;
        float s = e[r] * C;
        if (qv && (key <= q)) s = -1e30f;       // key<L implied by key<=q<L
        e[r] = s;
        pm = fmaxf(pm, s);
      }
    } else {
      #pragma unroll
      for (int r = 0; r < 16; ++r) {
        const float s = e[r] * C;
        e[r] = s;
        pm = fmaxf(pm, s);
      }
    }
    pm = fmaxf(pm, __shfl_xor(pm, 32));

    // --- defer-max online softmax (THR=8 in log2 domain) ---
    const bool need = !__all(pm <= mrow + 8.0f);
    if (need) {
      const float mn = fmaxf(mrow, pm);
      const float a = exp2f(mrow - mn);
      #pragma unroll
      for (int r = 0; r < 16; ++r) { o0[r] *= a; o1[r] *= a; }
      lrow *= a;
      mrow = mn;
    }
    float sum = 0.f;
    #pragma unroll
    for (int r = 0; r < 16; ++r) {
      const float pe = exp2f(e[r] - mrow);
      e[r] = pe; sum += pe;
    }
    sum += __shfl_xor(sum, 32);
    lrow += sum;

    // --- P -> bf16 B-frags: pack pairs (f2bf) + cross-half exchange (shfl) ---
    bf16x8 pbf[2];
    #pragma unroll
    for (int kc = 0; kc < 2; ++kc) {
      const unsigned wA = pack2(e[8*kc+0], e[8*kc+1]);
      const unsigned wB = pack2(e[8*kc+2], e[8*kc+3]);
      const unsigned wC = pack2(e[8*kc+4], e[8*kc+5]);
      const unsigned wD = pack2(e[8*kc+6], e[8*kc+7]);
      const unsigned pA = __shfl_xor(wA, 32);
      const unsigned pB = __shfl_xor(wB, 32);
      const unsigned pC = __shfl_xor(wC, 32);
      const unsigned pD = __shfl_xor(wD, 32);
      union { unsigned u[4]; bf16x8 v; } pk;
      pk.u[0] = hi ? pC : wA;
      pk.u[1] = hi ? pD : wB;
      pk.u[2] = hi ? wC : pA;
      pk.u[3] = hi ? wD : pB;
      pbf[kc] = pk.v;
    }

    // --- PV: O^T += V^T * P ---
    __builtin_amdgcn_s_setprio(1);
    #pragma unroll
    for (int kc = 0; kc < 2; ++kc) {
      const bf16x8 vf0 = *(const bf16x8*)&vp[l31 * SLEN + kb0 + kc * 16 + hi * 8];
      const bf16x8 vf1 = *(const bf16x8*)&vp[(32 + l31) * SLEN + kb0 + kc * 16 + hi * 8];
      o0 = MFMA32(vf0, pbf[kc], o0);
      o1 = MFMA32(vf1, pbf[kc], o1);
    }
    __builtin_amdgcn_s_setprio(0);
  }

  // ---------------- 2-wave flash merge through LDS ----------------
  __shared__ float ml[2][2][32];                 // [wave][m|l][q]
  __shared__ __align__(16) float obuf[64][34];   // +2 pad: 2-way banks (free)
  if (hi == 0) { ml[w][0][l31] = mrow; ml[w][1][l31] = lrow; }
  // each wave deposits the half it will NOT store (unscaled)
  if (w == 0) {
    #pragma unroll
    for (int r = 0; r < 16; ++r) obuf[l][16 + r] = o1[r];
  } else {
    #pragma unroll
    for (int r = 0; r < 16; ++r) obuf[l][r] = o0[r];
  }
  __syncthreads();
  const float m0 = ml[0][0][l31], m1 = ml[1][0][l31];
  const float l0 = ml[0][1][l31], l1 = ml[1][1][l31];
  const float mn = fmaxf(m0, m1);
  const float s0 = exp2f(m0 - mn), s1 = exp2f(m1 - mn);
  const float inv = 1.0f / (l0 * s0 + l1 * s1);
  unsigned short* yrow = yb + (size_t)(b * SLEN + q) * EDIM + h * DHEAD;
  if (w == 0) {
    // final d<32: own o0 (scale s0) + partner's o0 from LDS (scale s1)
    #pragma unroll
    for (int rq = 0; rq < 4; ++rq) {
      ushort4 st;
      st.x = f2bf((o0[4*rq+0] * s0 + obuf[l][4*rq+0] * s1) * inv);
      st.y = f2bf((o0[4*rq+1] * s0 + obuf[l][4*rq+1] * s1) * inv);
      st.z = f2bf((o0[4*rq+2] * s0 + obuf[l][4*rq+2] * s1) * inv);
      st.w = f2bf((o0[4*rq+3] * s0 + obuf[l][4*rq+3] * s1) * inv);
      *(ushort4*)&yrow[8*rq + 4*hi] = st;
    }
  } else {
    // final d>=32: partner's o1 from LDS (scale s0) + own o1 (scale s1)
    #pragma unroll
    for (int rq = 0; rq < 4; ++rq) {
      ushort4 st;
      st.x = f2bf((obuf[l][16+4*rq+0] * s0 + o1[4*rq+0] * s1) * inv);
      st.y = f2bf((obuf[l][16+4*rq+1] * s0 + o1[4*rq+1] * s1) * inv);
      st.z = f2bf((obuf[l][16+4*rq+2] * s0 + o1[4*rq+2] * s1) * inv);
      st.w = f2bf((obuf[l][16+4*rq+3] * s0 + o1[4*rq+3] * s1) * inv);
      *(ushort4*)&yrow[32 + 8*rq + 4*hi] = st;
    }
  }
}

// ---------------- launch ----------------
extern "C" void kernel_launch(void* const* d_in, const int* in_sizes, int n_in,
                              void* d_out, int out_size, void* d_ws, size_t ws_size,
                              hipStream_t stream) {
  const float* x    = (const float*)d_in[0];
  const int*   mask = (const int*)d_in[1];
  const float* wqkv = (const float*)d_in[2];
  const float* bqkv = (const float*)d_in[3];
  const float* wout = (const float*)d_in[4];
  const float* bout = (const float*)d_in[5];
  float* out = (float*)d_out;

  char* ws = (char*)d_ws;
  const size_t SZ_X   = (size_t)BATCH * SLEN * EDIM * 2;   // 8MB
  const size_t SZ_WQ  = (size_t)3 * EDIM * EDIM * 2;       // 6MB
  const size_t SZ_WO  = (size_t)EDIM * EDIM * 2;           // 2MB
  const size_t SZ_QKV = (size_t)BATCH * NHEADS * SLEN * DHEAD * 2;  // 8MB each

  unsigned short* xb   = (unsigned short*)ws;               ws += SZ_X;
  unsigned short* wqb  = (unsigned short*)ws;               ws += SZ_WQ;
  unsigned short* wob  = (unsigned short*)ws;               ws += SZ_WO;
  unsigned short* qbuf = (unsigned short*)ws;               ws += SZ_QKV;
  unsigned short* kbuf = (unsigned short*)ws;               ws += SZ_QKV;
  unsigned short* vbuf = (unsigned short*)ws;               ws += SZ_QKV;
  unsigned short* ybuf = (unsigned short*)ws;               ws += SZ_X;
  int* Lbuf = (int*)ws;

  prep_cast<<<8192, 256, 0, stream>>>(x, wqkv, wout, xb, wqb, wob);
  mask_sum<<<BATCH, 256, 0, stream>>>(mask, Lbuf);
  gemm_bt<0><<<(4096 / 128) * (3072 / 128), 256, 0, stream>>>(
      xb, wqb, 4096, 3072, 1024, bqkv, nullptr, qbuf, kbuf, vbuf);
  attn<<<BATCH * NHEADS * (SLEN / 32), 128, 0, stream>>>(qbuf, kbuf, vbuf, Lbuf, ybuf);
  gemm_bt<1><<<(4096 / 128) * (1024 / 128), 256, 0, stream>>>(
      ybuf, wob, 4096, 1024, 1024, bout, out, nullptr, nullptr, nullptr);
}

// Round 6
// 230.370 us; speedup vs baseline: 1.0630x; 1.0630x over previous
//
#include <hip/hip_runtime.h>

// Fused MHA: x(4,1024,1024) fp32, mask(4,1024) i32, w_qkv(3072,1024), b_qkv,
// w_out(1024,1024), b_out -> out(4,1024,1024) fp32.
// Pipeline: prep-cast -> mask-sum -> qkv GEMM (bf16 MFMA) -> flash attn -> out GEMM.
// R6: attn = 4-wave KV-split (t == w mod 4), cross-iter K-register prefetch +
//     early V issue (hide L2 latency under softmax), pairwise-tree LDS merge.

#define NHEADS 16
#define DHEAD  64
#define EDIM   1024
#define SLEN   1024
#define BATCH  4

typedef short bf16x8 __attribute__((ext_vector_type(8)));
typedef float f32x4  __attribute__((ext_vector_type(4)));
typedef float f32x16 __attribute__((ext_vector_type(16)));

#define MFMA_BF16(a,b,c) __builtin_amdgcn_mfma_f32_16x16x32_bf16((a),(b),(c),0,0,0)
#define MFMA32(a,b,c)    __builtin_amdgcn_mfma_f32_32x32x16_bf16((a),(b),(c),0,0,0)

typedef const __attribute__((address_space(1))) void gvoid_t;
typedef __attribute__((address_space(3))) void lvoid_t;

__device__ __forceinline__ unsigned short f2bf(float x) {
  union { float f; unsigned int u; } v; v.f = x;
  unsigned int r = v.u + 0x7fffu + ((v.u >> 16) & 1u);
  return (unsigned short)(r >> 16);
}

__device__ __forceinline__ unsigned pack2(float lo, float hi) {
  return (unsigned)f2bf(lo) | ((unsigned)f2bf(hi) << 16);
}

__device__ __forceinline__ void gl2lds16(const void* g, void* l) {
  __builtin_amdgcn_global_load_lds((gvoid_t*)g, (lvoid_t*)l, 16, 0, 0);
}

// ---------------- prep: fp32 -> bf16 casts ----------------
__global__ __launch_bounds__(256) void prep_cast(
    const float* __restrict__ x, const float* __restrict__ wq,
    const float* __restrict__ wo,
    unsigned short* __restrict__ xb, unsigned short* __restrict__ wqb,
    unsigned short* __restrict__ wob) {
  int i = blockIdx.x * 256 + threadIdx.x;
  const int NX  = BATCH * SLEN * EDIM / 4;   // 1048576
  const int NW1 = 3 * EDIM * EDIM / 4;       // 786432
  const float4* src; unsigned short* dst; int j;
  if (i < NX)           { src = (const float4*)x;  dst = xb;  j = i; }
  else if (i < NX+NW1)  { src = (const float4*)wq; dst = wqb; j = i - NX; }
  else                  { src = (const float4*)wo; dst = wob; j = i - NX - NW1; }
  float4 v = src[j];
  ushort4 o;
  o.x = f2bf(v.x); o.y = f2bf(v.y); o.z = f2bf(v.z); o.w = f2bf(v.w);
  ((ushort4*)dst)[j] = o;
}

// ---------------- mask row-sum: L[b] ----------------
__global__ __launch_bounds__(256) void mask_sum(const int* __restrict__ mask,
                                                int* __restrict__ L) {
  int b = blockIdx.x;
  int t = threadIdx.x;
  int s = 0;
  for (int i = t; i < SLEN; i += 256) s += mask[b * SLEN + i];
  #pragma unroll
  for (int m = 1; m < 64; m <<= 1) s += __shfl_xor(s, m);
  __shared__ int part[4];
  if ((t & 63) == 0) part[t >> 6] = s;
  __syncthreads();
  if (t == 0) L[b] = part[0] + part[1] + part[2] + part[3];
}

// ---------------- GEMM C = A @ B^T (A:[M][K], B:[N][K], bf16, m97 structure) ----
template<int EPI>
__global__ __launch_bounds__(256) void gemm_bt(
    const unsigned short* __restrict__ A, const unsigned short* __restrict__ B,
    int M, int N, int K,
    const float* __restrict__ bias,
    float* __restrict__ outf,
    unsigned short* __restrict__ qb, unsigned short* __restrict__ kb,
    unsigned short* __restrict__ vb) {
  __shared__ __align__(16) unsigned short lds_a[128 * 32];
  __shared__ __align__(16) unsigned short lds_b[128 * 32];
  const int tid = threadIdx.x;
  const int w = tid >> 6, l = tid & 63;
  const int g = l >> 4, ln = l & 15;
  const int ntile = N >> 7;
  const int tm = blockIdx.x / ntile, tn = blockIdx.x % ntile;
  const int mBase = tm << 7, nBase = tn << 7;
  const int wr = w >> 1, wc = w & 1;

  f32x4 zz = {0.f, 0.f, 0.f, 0.f};
  f32x4 acc[4][4];
  #pragma unroll
  for (int m = 0; m < 4; ++m)
    #pragma unroll
    for (int n = 0; n < 4; ++n) acc[m][n] = zz;

  const int u0 = tid, u1 = tid + 256;
  const int r0 = u0 >> 2, c0 = (u0 & 3) << 3;
  const int r1 = u1 >> 2, c1 = (u1 & 3) << 3;
  const unsigned short* Ab = A + mBase * K;
  const unsigned short* Bb = B + nBase * K;
  unsigned short* da0 = &lds_a[(w * 64) * 8];
  unsigned short* da1 = &lds_a[(256 + w * 64) * 8];
  unsigned short* db0 = &lds_b[(w * 64) * 8];
  unsigned short* db1 = &lds_b[(256 + w * 64) * 8];

  for (int k0 = 0; k0 < K; k0 += 32) {
    gl2lds16(Ab + r0 * K + k0 + c0, da0);
    gl2lds16(Ab + r1 * K + k0 + c1, da1);
    gl2lds16(Bb + r0 * K + k0 + c0, db0);
    gl2lds16(Bb + r1 * K + k0 + c1, db1);
    __syncthreads();
    bf16x8 af[4], bfr[4];
    #pragma unroll
    for (int m = 0; m < 4; ++m)
      af[m] = *(const bf16x8*)&lds_a[(wr * 64 + m * 16 + ln) * 32 + g * 8];
    #pragma unroll
    for (int n = 0; n < 4; ++n)
      bfr[n] = *(const bf16x8*)&lds_b[(wc * 64 + n * 16 + ln) * 32 + g * 8];
    #pragma unroll
    for (int m = 0; m < 4; ++m)
      #pragma unroll
      for (int n = 0; n < 4; ++n)
        acc[m][n] = MFMA_BF16(af[m], bfr[n], acc[m][n]);
    __syncthreads();
  }

  #pragma unroll
  for (int m = 0; m < 4; ++m) {
    const int rowb = mBase + wr * 64 + m * 16 + g * 4;
    #pragma unroll
    for (int n = 0; n < 4; ++n) {
      const int col = nBase + wc * 64 + n * 16 + ln;
      const float bv = bias[col];
      #pragma unroll
      for (int r = 0; r < 4; ++r) {
        const float vv = acc[m][n][r] + bv;
        const int row = rowb + r;
        if (EPI == 0) {
          const int part = col >> 10;          // 0=q,1=k,2=v
          const int c = col & 1023;
          const int hh = c >> 6, d = c & 63;
          const int bb = row >> 10, s = row & 1023;
          const int bh = bb * NHEADS + hh;
          const unsigned short hv = f2bf(vv);
          if (part == 0)      qb[(bh * SLEN + s) * DHEAD + d] = hv;
          else if (part == 1) kb[(bh * SLEN + s) * DHEAD + d] = hv;
          else                vb[(bh * DHEAD + d) * SLEN + s] = hv;  // V^T
        } else {
          outf[row * N + col] = vv;
        }
      }
    }
  }
}

// ---------------- flash attention (swapped-operand 32x32, KV-split x4) --------
// 256-thr blocks = 4 waves; wave w does tiles t == w (mod 4) above tstart.
// S^T = mfma(K, Q): lane holds q=lane&31, keys crow(r,hi)=(r&3)+8*(r>>2)+4*hi.
// O^T = mfma(V^T, P): lane holds q=lane&31, d=crow(r,hi) (+32 for o1).
// Cross-iter K prefetch into regs; V issued at top of body (latency hidden).
__global__ __launch_bounds__(256) void attn(
    const unsigned short* __restrict__ qb, const unsigned short* __restrict__ kb,
    const unsigned short* __restrict__ vb, const int* __restrict__ Lp,
    unsigned short* __restrict__ yb) {
  const int bid = blockIdx.x;
  const int lid = (bid & 7) * 256 + (bid >> 3);   // XCD-chunked swizzle (2048%8==0)
  const int bh = lid >> 5, qw = lid & 31;
  const int b = bh >> 4, h = bh & 15;
  const int L = Lp[b];
  const int tid = threadIdx.x;
  const int w = tid >> 6, l = tid & 63;
  const int l31 = l & 31, hi = l >> 5;
  const int q = qw * 32 + l31;

  const unsigned short* qp = qb + (size_t)bh * SLEN * DHEAD;
  const unsigned short* kp = kb + (size_t)bh * SLEN * DHEAD;
  const unsigned short* vp = vb + (size_t)bh * DHEAD * SLEN;

  bf16x8 qf[4];
  #pragma unroll
  for (int c = 0; c < 4; ++c)
    qf[c] = *(const bf16x8*)&qp[q * DHEAD + c * 16 + hi * 8];

  f32x16 o0 = {}; f32x16 o1 = {};
  float mrow = -__builtin_inff(), lrow = 0.f;   // log2 domain
  const bool qv = q < L;
  const float C = 0.18033688011112042f;          // 0.125 * log2(e)

  const bool allQ  = (qw * 32 + 31) < L;
  const bool noneQ = (qw * 32) >= L;
  const int tstart = (allQ && L < SLEN) ? qw : 0;     // fully-masked tiles skipped
  const int tlo = tstart + ((w - tstart) & 3);        // first tile for this wave

  // prologue K prefetch (clamped tile index keeps addresses in-bounds)
  const int tp = tlo < 32 ? tlo : 31;
  bf16x8 kcur[4];
  #pragma unroll
  for (int c = 0; c < 4; ++c)
    kcur[c] = *(const bf16x8*)&kp[(tp * 32 + l31) * DHEAD + c * 16 + hi * 8];

  for (int t = tlo; t < 32; t += 4) {
    const int kb0 = t * 32;
    const int tn = (t + 4 < 32) ? (t + 4) : t;        // next-tile prefetch (dup ok)
    bf16x8 knxt[4];
    #pragma unroll
    for (int c = 0; c < 4; ++c)
      knxt[c] = *(const bf16x8*)&kp[(tn * 32 + l31) * DHEAD + c * 16 + hi * 8];
    bf16x8 vf0[2], vf1[2];
    #pragma unroll
    for (int kc = 0; kc < 2; ++kc) {
      vf0[kc] = *(const bf16x8*)&vp[l31 * SLEN + kb0 + kc * 16 + hi * 8];
      vf1[kc] = *(const bf16x8*)&vp[(32 + l31) * SLEN + kb0 + kc * 16 + hi * 8];
    }

    // --- QK^T (swapped): A = K rows (key=lane&31), B = Q ---
    f32x16 e = {};
    __builtin_amdgcn_s_setprio(1);
    #pragma unroll
    for (int c = 0; c < 4; ++c) e = MFMA32(kcur[c], qf[c], e);
    __builtin_amdgcn_s_setprio(0);

    // --- scale (exp2 domain) + mask (diag region only) + row max ---
    const bool domask = (!noneQ) && (t <= qw);
    float pm = -__builtin_inff();
    if (domask) {
      #pragma unroll
      for (int r = 0; r < 16; ++r) {
        const int key = kb0 + (r & 3) + 8 * (r >> 2) + 4 * hi;
        float s = e[r] * C;
        if (qv && (key <= q)) s = -1e30f;
        e[r] = s;
        pm = fmaxf(pm, s);
      }
    } else {
      #pragma unroll
      for (int r = 0; r < 16; ++r) {
        const float s = e[r] * C;
        e[r] = s;
        pm = fmaxf(pm, s);
      }
    }
    pm = fmaxf(pm, __shfl_xor(pm, 32));

    // --- defer-max online softmax (THR=8 in log2 domain) ---
    const bool need = !__all(pm <= mrow + 8.0f);
    if (need) {
      const float mn = fmaxf(mrow, pm);
      const float a = exp2f(mrow - mn);
      #pragma unroll
      for (int r = 0; r < 16; ++r) { o0[r] *= a; o1[r] *= a; }
      lrow *= a;
      mrow = mn;
    }
    float sum = 0.f;
    #pragma unroll
    for (int r = 0; r < 16; ++r) {
      const float pe = exp2f(e[r] - mrow);
      e[r] = pe; sum += pe;
    }
    sum += __shfl_xor(sum, 32);
    lrow += sum;

    // --- P -> bf16 B-frags: pack pairs + cross-half exchange ---
    bf16x8 pbf[2];
    #pragma unroll
    for (int kc = 0; kc < 2; ++kc) {
      const unsigned wA = pack2(e[8*kc+0], e[8*kc+1]);
      const unsigned wB = pack2(e[8*kc+2], e[8*kc+3]);
      const unsigned wC = pack2(e[8*kc+4], e[8*kc+5]);
      const unsigned wD = pack2(e[8*kc+6], e[8*kc+7]);
      const unsigned pA = __shfl_xor(wA, 32);
      const unsigned pB = __shfl_xor(wB, 32);
      const unsigned pC = __shfl_xor(wC, 32);
      const unsigned pD = __shfl_xor(wD, 32);
      union { unsigned u[4]; bf16x8 v; } pk;
      pk.u[0] = hi ? pC : wA;
      pk.u[1] = hi ? pD : wB;
      pk.u[2] = hi ? wC : pA;
      pk.u[3] = hi ? wD : pB;
      pbf[kc] = pk.v;
    }

    // --- PV: O^T += V^T * P ---
    __builtin_amdgcn_s_setprio(1);
    #pragma unroll
    for (int kc = 0; kc < 2; ++kc) {
      o0 = MFMA32(vf0[kc], pbf[kc], o0);
      o1 = MFMA32(vf1[kc], pbf[kc], o1);
    }
    __builtin_amdgcn_s_setprio(0);

    #pragma unroll
    for (int c = 0; c < 4; ++c) kcur[c] = knxt[c];
  }

  // ---------------- 4-wave pairwise-tree flash merge ----------------
  __shared__ float mls[4][2][32];
  __shared__ __align__(16) float obuf[2][32][65];   // stride 65: conflict-free
  if (hi == 0) { mls[w][0][l31] = mrow; mls[w][1][l31] = lrow; }
  __syncthreads();
  const float m0 = mls[0][0][l31], m1 = mls[1][0][l31];
  const float m2 = mls[2][0][l31], m3 = mls[3][0][l31];
  const float mstar = fmaxf(fmaxf(m0, m1), fmaxf(m2, m3));
  const float denom = mls[0][1][l31] * exp2f(m0 - mstar)
                    + mls[1][1][l31] * exp2f(m1 - mstar)
                    + mls[2][1][l31] * exp2f(m2 - mstar)
                    + mls[3][1][l31] * exp2f(m3 - mstar);
  const float sw = exp2f(mrow - mstar) / denom;     // own normalized scale
  // scale own contribution
  #pragma unroll
  for (int r = 0; r < 16; ++r) { o0[r] *= sw; o1[r] *= sw; }
  // round 1: waves 2,3 deposit
  if (w >= 2) {
    #pragma unroll
    for (int r = 0; r < 16; ++r) {
      const int d = (r & 3) + 8 * (r >> 2) + 4 * hi;
      obuf[w - 2][l31][d]      = o0[r];
      obuf[w - 2][l31][d + 32] = o1[r];
    }
  }
  __syncthreads();
  if (w < 2) {
    #pragma unroll
    for (int r = 0; r < 16; ++r) {
      const int d = (r & 3) + 8 * (r >> 2) + 4 * hi;
      o0[r] += obuf[w][l31][d];
      o1[r] += obuf[w][l31][d + 32];
    }
  }
  __syncthreads();
  // round 2: wave 1 deposits its pair-sum
  if (w == 1) {
    #pragma unroll
    for (int r = 0; r < 16; ++r) {
      const int d = (r & 3) + 8 * (r >> 2) + 4 * hi;
      obuf[0][l31][d]      = o0[r];
      obuf[0][l31][d + 32] = o1[r];
    }
  }
  __syncthreads();
  if (w == 0) {
    #pragma unroll
    for (int r = 0; r < 16; ++r) {
      const int d = (r & 3) + 8 * (r >> 2) + 4 * hi;
      o0[r] += obuf[0][l31][d];
      o1[r] += obuf[0][l31][d + 32];
    }
    unsigned short* yrow = yb + (size_t)(b * SLEN + q) * EDIM + h * DHEAD;
    #pragma unroll
    for (int rq = 0; rq < 4; ++rq) {
      ushort4 s0, s1;
      s0.x = f2bf(o0[4*rq+0]); s0.y = f2bf(o0[4*rq+1]);
      s0.z = f2bf(o0[4*rq+2]); s0.w = f2bf(o0[4*rq+3]);
      s1.x = f2bf(o1[4*rq+0]); s1.y = f2bf(o1[4*rq+1]);
      s1.z = f2bf(o1[4*rq+2]); s1.w = f2bf(o1[4*rq+3]);
      *(ushort4*)&yrow[8*rq + 4*hi]      = s0;
      *(ushort4*)&yrow[32 + 8*rq + 4*hi] = s1;
    }
  }
}

// ---------------- launch ----------------
extern "C" void kernel_launch(void* const* d_in, const int* in_sizes, int n_in,
                              void* d_out, int out_size, void* d_ws, size_t ws_size,
                              hipStream_t stream) {
  const float* x    = (const float*)d_in[0];
  const int*   mask = (const int*)d_in[1];
  const float* wqkv = (const float*)d_in[2];
  const float* bqkv = (const float*)d_in[3];
  const float* wout = (const float*)d_in[4];
  const float* bout = (const float*)d_in[5];
  float* out = (float*)d_out;

  char* ws = (char*)d_ws;
  const size_t SZ_X   = (size_t)BATCH * SLEN * EDIM * 2;   // 8MB
  const size_t SZ_WQ  = (size_t)3 * EDIM * EDIM * 2;       // 6MB
  const size_t SZ_WO  = (size_t)EDIM * EDIM * 2;           // 2MB
  const size_t SZ_QKV = (size_t)BATCH * NHEADS * SLEN * DHEAD * 2;  // 8MB each

  unsigned short* xb   = (unsigned short*)ws;               ws += SZ_X;
  unsigned short* wqb  = (unsigned short*)ws;               ws += SZ_WQ;
  unsigned short* wob  = (unsigned short*)ws;               ws += SZ_WO;
  unsigned short* qbuf = (unsigned short*)ws;               ws += SZ_QKV;
  unsigned short* kbuf = (unsigned short*)ws;               ws += SZ_QKV;
  unsigned short* vbuf = (unsigned short*)ws;               ws += SZ_QKV;
  unsigned short* ybuf = (unsigned short*)ws;               ws += SZ_X;
  int* Lbuf = (int*)ws;

  prep_cast<<<8192, 256, 0, stream>>>(x, wqkv, wout, xb, wqb, wob);
  mask_sum<<<BATCH, 256, 0, stream>>>(mask, Lbuf);
  gemm_bt<0><<<(4096 / 128) * (3072 / 128), 256, 0, stream>>>(
      xb, wqb, 4096, 3072, 1024, bqkv, nullptr, qbuf, kbuf, vbuf);
  attn<<<BATCH * NHEADS * (SLEN / 32), 256, 0, stream>>>(qbuf, kbuf, vbuf, Lbuf, ybuf);
  gemm_bt<1><<<(4096 / 128) * (1024 / 128), 256, 0, stream>>>(
      ybuf, wob, 4096, 1024, 1024, bout, out, nullptr, nullptr, nullptr);
}